// Round 1
// baseline (2624.076 us; speedup 1.0000x reference)
//
#include <hip/hip_runtime.h>
#include <hip/hip_fp16.h>
#include <cstdio>

// EmbeddingCellLSTM: B=32, S=2048, IN=64, EMB=32, H=256, 4H=1024
//  k1 pack_kernel : W_hh fp32 -> i8 (scale 2032) packed dwords for v_dot4_i32_i8.
//  k2 zx_kernel   : zx[b][s][row] = (concat(x,emb) @ W_ih^T + b) fp16, natural row order.
//  k3 lstm_kernel : 32 blocks (1/batch) x 1024 thr (16 waves). Thread = (unit u, K-quarter q):
//                   owns all 4 gate rows of u over K in [64q,64q+64). 64 VGPRs of i8 weights.
//                   Per step: 4 broadcast ds_read_b128 of h-quarter, 64 v_dot4 (8 chains x 8),
//                   cross-quarter reduce via ds_swizzle(xor16) + ds_bpermute(xor32). Lane then
//                   holds i,f,g,o of its unit -> no cndmask tree, no gate-gather bpermute.
//                   c/h update replicated 4x across quarters; q==0 lanes write i8 h feedback
//                   (scale 127, 512B double-buffered LDS) + fp32 out. 1 __syncthreads()/step.
//                   Rationale: mfma_i32_16x16x64 on a matvec wastes 16x (N-replicas) ->
//                   ~200 useful MACs/cyc/CU; v_dot4 gives 512/cyc/CU on the VALU pipe.

#define WPK_OFF (134217728u)   // zx = 32*2048*1024*2 bytes, then wpk 256 KB

typedef int v4i __attribute__((ext_vector_type(4)));

static __device__ __forceinline__ unsigned short f16bits(float v) {
  _Float16 h = (_Float16)v;
  return __builtin_bit_cast(unsigned short, h);
}

static __device__ __forceinline__ float h2f(unsigned short b) {
  return (float)__builtin_bit_cast(_Float16, b);
}

#define DOT4(a, b, c) __builtin_amdgcn_sdot4((a), (b), (c), false)

// ---------------- k1: pack W_hh -> i8 dot4 dwords ----------------
// wpk[tid] : tid = t*64 + dw ; t = owning k3 thread, dw = g*16 + kk.
// From t: w=t>>6, lane=t&63, q=lane>>4, n=lane&15, u=w*16+n.
// Dword holds W[g*256+u][q*64 + kk*4 + e] in byte e. wq = rint(w*2032), |w|<1/16 -> |wq|<=127.
__global__ __launch_bounds__(1024) void pack_kernel(const float* __restrict__ Whh,
                                                    int* __restrict__ wpk) {
  int tid = blockIdx.x * 1024 + threadIdx.x;    // 0..65535
  int t = tid >> 6, dw = tid & 63;
  int g = dw >> 4, kk = dw & 15;
  int lane = t & 63, w = t >> 6, q = lane >> 4, n = lane & 15;
  int u = w * 16 + n;
  int row = g * 256 + u;
  int col0 = q * 64 + kk * 4;
  const float* src = Whh + (size_t)row * 256 + col0;
  unsigned int v = 0;
#pragma unroll
  for (int e = 0; e < 4; e++) {
    int qv = (int)rintf(src[e] * 2032.0f);
    v |= ((unsigned int)(qv & 255)) << (8 * e);
  }
  wpk[tid] = (int)v;
}

// ---------------- k2: zx = concat(x,emb) @ W_ih^T + b (fp16, natural row order) ----------------
__global__ __launch_bounds__(256) void zx_kernel(const float* __restrict__ x,
                                                 const float* __restrict__ emb,
                                                 const float* __restrict__ Wih,
                                                 const float* __restrict__ bias,
                                                 unsigned short* __restrict__ zx) {
  __shared__ __align__(16) float XeT[96][68];
  __shared__ __align__(16) float WT[96][68];
  int mt = blockIdx.x, nt = blockIdx.y;     // 1024 x 16
  int m0 = mt * 64, n0 = nt * 64;
  int tid = threadIdx.x;
  for (int idx = tid; idx < 6144; idx += 256) {
    int r = idx / 96, k = idx - r * 96;
    size_t m = (size_t)(m0 + r);
    float v = (k < 64) ? x[m * 64 + k] : emb[m * 32 + (k - 64)];
    XeT[k][r] = v;
  }
  for (int idx = tid; idx < 6144; idx += 256) {
    int c = idx / 96, k = idx - c * 96;
    WT[k][c] = Wih[(size_t)(n0 + c) * 96 + k];
  }
  __syncthreads();
  int ty = tid >> 4, tx = tid & 15;
  int r0 = ty * 4, c0 = tx * 4;
  float acc[4][4] = {};
  for (int k = 0; k < 96; k++) {
    float4 a = *(const float4*)&XeT[k][r0];
    float4 w = *(const float4*)&WT[k][c0];
    float av[4] = {a.x, a.y, a.z, a.w};
    float wv[4] = {w.x, w.y, w.z, w.w};
#pragma unroll
    for (int i = 0; i < 4; i++)
#pragma unroll
      for (int jj = 0; jj < 4; jj++) acc[i][jj] += av[i] * wv[jj];
  }
#pragma unroll
  for (int i = 0; i < 4; i++) {
    size_t m = (size_t)(m0 + r0 + i);
#pragma unroll
    for (int jj = 0; jj < 4; jj++) {
      int col = n0 + c0 + jj;
      zx[m * 1024 + (size_t)col] = f16bits(acc[i][jj] + bias[col]);
    }
  }
}

// ---------------- k3: persistent per-batch LSTM (v_dot4 i8, register-resident W) ----------------
__global__ __launch_bounds__(1024, 4) void lstm_kernel(const unsigned short* __restrict__ zx,
                                                       const int* __restrict__ wpk,
                                                       float* __restrict__ out) {
  __shared__ __align__(16) char hq[2][256];
  const int t = threadIdx.x, b = blockIdx.x;
  const int lane = t & 63, w = t >> 6, q = lane >> 4, n = lane & 15;
  const int u = w * 16 + n;                      // unit 0..255

  // register-resident weights: 4 gates x 16 dwords (K-quarter) = 64 VGPRs
  int wf[64];
  {
    const int* wp = wpk + t * 64;
#pragma unroll
    for (int i = 0; i < 16; i++) *(v4i*)&wf[i * 4] = *(const v4i*)&wp[i * 4];
  }

  if (t < 128) ((unsigned int*)hq)[t] = 0;       // zero both h buffers (2x256 i8)
  __syncthreads();

  const float dq = 1.0f / (2032.0f * 127.0f);
  const unsigned short* zp = zx + (size_t)b * (2048u * 1024u) + u;
  float* op = out + (size_t)b * (2048u * 256u) + u;
  char* hw = &hq[0][u];
  const bool wr = (q == 0);
  const int bp32 = ((lane ^ 32) & 63) << 2;      // bpermute byte index: lane^32

  unsigned short za0 = zp[0], za1 = zp[256], za2 = zp[512], za3 = zp[768];
  float cst = 0.f, hlast = 0.f;

#pragma unroll 2
  for (int s = 0; s < 2048; s++) {
    // prefetch next step's zx (1 step ahead; used ~a full step later)
    int sp = s + 1; if (sp > 2047) sp = 2047;
    const unsigned short* zn = zp + ((size_t)sp << 10);
    unsigned short zb0 = zn[0], zb1 = zn[256], zb2 = zn[512], zb3 = zn[768];

    // h quarter (64 i8 = 16 dwords), 16-lane-broadcast reads
    const char* hc = &hq[s & 1][q * 64];
    int hd[16];
#pragma unroll
    for (int kk = 0; kk < 4; kk++) *(v4i*)&hd[kk * 4] = *(const v4i*)(hc + kk * 16);

    // 8 independent dot4 chains of depth 8
    int a0a = 0, a0b = 0, a1a = 0, a1b = 0, a2a = 0, a2b = 0, a3a = 0, a3b = 0;
#pragma unroll
    for (int kk = 0; kk < 8; kk++) {
      a0a = DOT4(wf[0 * 16 + kk], hd[kk], a0a);
      a0b = DOT4(wf[0 * 16 + 8 + kk], hd[8 + kk], a0b);
      a1a = DOT4(wf[1 * 16 + kk], hd[kk], a1a);
      a1b = DOT4(wf[1 * 16 + 8 + kk], hd[8 + kk], a1b);
      a2a = DOT4(wf[2 * 16 + kk], hd[kk], a2a);
      a2b = DOT4(wf[2 * 16 + 8 + kk], hd[8 + kk], a2b);
      a3a = DOT4(wf[3 * 16 + kk], hd[kk], a3a);
      a3b = DOT4(wf[3 * 16 + 8 + kk], hd[8 + kk], a3b);
    }
    int a0 = a0a + a0b, a1 = a1a + a1b, a2 = a2a + a2b, a3 = a3a + a3b;

    // cross-quarter reduce: xor16 (ds_swizzle within 32-lane groups) + xor32 (ds_bpermute)
    a0 += __builtin_amdgcn_ds_swizzle(a0, 0x401F);
    a1 += __builtin_amdgcn_ds_swizzle(a1, 0x401F);
    a2 += __builtin_amdgcn_ds_swizzle(a2, 0x401F);
    a3 += __builtin_amdgcn_ds_swizzle(a3, 0x401F);
    a0 += __builtin_amdgcn_ds_bpermute(bp32, a0);
    a1 += __builtin_amdgcn_ds_bpermute(bp32, a1);
    a2 += __builtin_amdgcn_ds_bpermute(bp32, a2);
    a3 += __builtin_amdgcn_ds_bpermute(bp32, a3);

    // full gate set in-lane: i,f,g,o of unit u
    float z0 = (float)a0 * dq + h2f(za0);
    float z1 = (float)a1 * dq + h2f(za1);
    float z2 = (float)a2 * dq + h2f(za2);
    float z3 = (float)a3 * dq + h2f(za3);
    float si = __builtin_amdgcn_rcpf(1.f + __builtin_amdgcn_exp2f(-1.44269504f * z0));
    float sf = __builtin_amdgcn_rcpf(1.f + __builtin_amdgcn_exp2f(-1.44269504f * z1));
    float tg = 2.f * __builtin_amdgcn_rcpf(1.f + __builtin_amdgcn_exp2f(-2.88539008f * z2)) - 1.f;
    float so = __builtin_amdgcn_rcpf(1.f + __builtin_amdgcn_exp2f(-1.44269504f * z3));
    float cn = sf * cst + si * tg;
    float th = 2.f * __builtin_amdgcn_rcpf(1.f + __builtin_amdgcn_exp2f(-2.88539008f * cn)) - 1.f;
    float h = so * th;
    cst = cn;
    hlast = h;
    if (wr) {
      hw[((s & 1) ^ 1) * 256] = (char)(int)rintf(h * 127.0f);   // i8 h feedback
      op[(size_t)s * 256] = h;                                   // fp32 output
    }
    za0 = zb0; za1 = zb1; za2 = zb2; za3 = zb3;
    __syncthreads();
  }
  if (wr) {
    out[16777216u + (size_t)b * 256 + u] = hlast;          // final h
    out[16777216u + 8192u + (size_t)b * 256 + u] = cst;    // final c
  }
}

extern "C" void kernel_launch(void* const* d_in, const int* in_sizes, int n_in,
                              void* d_out, int out_size, void* d_ws, size_t ws_size,
                              hipStream_t stream) {
  const float* x = (const float*)d_in[0];
  const float* emb = (const float*)d_in[1];
  const float* W_ih = (const float*)d_in[2];
  const float* W_hh = (const float*)d_in[3];
  const float* bias = (const float*)d_in[4];
  float* out = (float*)d_out;
  char* ws = (char*)d_ws;

  unsigned short* zx = (unsigned short*)ws;
  int* wpk = (int*)(ws + WPK_OFF);

  size_t need = (size_t)WPK_OFF + 262144u;
  if (ws_size < need) {
    fprintf(stderr, "kernel_launch: ws too small: %zu < %zu\n", ws_size, need);
  }

  pack_kernel<<<dim3(64), dim3(1024), 0, stream>>>(W_hh, wpk);
  zx_kernel<<<dim3(1024, 16), dim3(256), 0, stream>>>(x, emb, W_ih, bias, zx);
  lstm_kernel<<<dim3(32), dim3(1024), 0, stream>>>(zx, wpk, out);
}

// Round 3
// 2282.613 us; speedup vs baseline: 1.1496x; 1.1496x over previous
//
#include <hip/hip_runtime.h>
#include <hip/hip_fp16.h>
#include <cstdio>

// EmbeddingCellLSTM: B=32, S=2048, IN=64, EMB=32, H=256, 4H=1024
//  Hybrid k3: z = Whh·h split across BOTH pipes per step:
//    K[0,128)   : i8 MFMA 16x16x64, N-broadcast (round-0 verified structure, 8 MFMA/wave)
//    K[128,256) : 32x v_dot4_i32_i8 per lane, weights mapped per-lane (unit,gate)
//  The MFMA select-tree leaves the K-low partial in exactly the lane that owns
//  (unit,gate) for the dot4 partial -> merge is one integer add. MFMA pipe ~653
//  cyc/step/SIMD, VALU ~940 -> overlapped (m114) vs 2016 (pure MFMA) / 2712 (pure dot4).
//  Register plan (128 cap @ 16 waves/CU, unified VGPR+AGPR): A-frags 32 + acc 16 in
//  AGPR-class, dot4 weights 32 VGPR, h staged 8 dwords at a time.
//  [Round 2: resubmission — round-1 bench hit GPUAcquisitionTimeout, kernel unmeasured.]

#define WPK_OFF (134217728u)   // zx = 32*2048*1024*2 bytes; then wpkA 128KB + wpkD 128KB

typedef int v4i __attribute__((ext_vector_type(4)));

static __device__ __forceinline__ unsigned short f16bits(float v) {
  _Float16 h = (_Float16)v;
  return __builtin_bit_cast(unsigned short, h);
}

#define DOT4(a, b, c) __builtin_amdgcn_sdot4((a), (b), (c), false)

// ---------------- k1: pack W_hh -> A-frags (K low half) + dot4 dwords (K high half) ----------------
// Blocks 0..7: A-tile ti = g*2+c (g=gate, c=K-chunk 0..1). thread t: w=t>>6, lane=t&63,
//   m=lane&15, q=lane>>4. A[m][k]: row=g*256+16w+m, k=c*64+q*16+j (byte j of 16B frag).
// Blocks 8..39: dot4 dwords. did=(blk-8)*1024+t = t3*32+idx. t3->w,lane,q,n; g=n&3,
//   uu=w*16+q*4+(n>>2); dword = W[g*256+uu][128+idx*4 .. +3].
// wq = rint(w*2032), |w|<1/16 -> |wq|<=127.
__global__ __launch_bounds__(1024) void pack_kernel(const float* __restrict__ Whh,
                                                    uint4* __restrict__ wpkA,
                                                    int* __restrict__ wpkD) {
  int blk = blockIdx.x, t = threadIdx.x;
  if (blk < 8) {
    int g = blk >> 1, c = blk & 1;
    int w = t >> 6, lane = t & 63, m = lane & 15, q = lane >> 4;
    int row = g * 256 + w * 16 + m;
    const float* src = Whh + (size_t)row * 256 + c * 64 + q * 16;
    unsigned int pk[4];
#pragma unroll
    for (int d = 0; d < 4; d++) {
      unsigned int v = 0;
#pragma unroll
      for (int e = 0; e < 4; e++) {
        int qv = (int)rintf(src[d * 4 + e] * 2032.0f);
        v |= ((unsigned int)(qv & 255)) << (8 * e);
      }
      pk[d] = v;
    }
    uint4 o; o.x = pk[0]; o.y = pk[1]; o.z = pk[2]; o.w = pk[3];
    wpkA[blk * 1024 + t] = o;
  } else {
    int did = (blk - 8) * 1024 + t;          // 0..32767
    int t3 = did >> 5, idx = did & 31;
    int w = t3 >> 6, lane = t3 & 63, q = lane >> 4, n = lane & 15;
    int g = n & 3, uu = w * 16 + q * 4 + (n >> 2);
    int row = g * 256 + uu;
    const float* src = Whh + (size_t)row * 256 + 128 + idx * 4;
    unsigned int v = 0;
#pragma unroll
    for (int e = 0; e < 4; e++) {
      int qv = (int)rintf(src[e] * 2032.0f);
      v |= ((unsigned int)(qv & 255)) << (8 * e);
    }
    wpkD[did] = (int)v;
  }
}

// ---------------- k2: zx = concat(x,emb) @ W_ih^T + b (fp16, natural row order) ----------------
__global__ __launch_bounds__(256) void zx_kernel(const float* __restrict__ x,
                                                 const float* __restrict__ emb,
                                                 const float* __restrict__ Wih,
                                                 const float* __restrict__ bias,
                                                 unsigned short* __restrict__ zx) {
  __shared__ __align__(16) float XeT[96][68];
  __shared__ __align__(16) float WT[96][68];
  int mt = blockIdx.x, nt = blockIdx.y;     // 1024 x 16
  int m0 = mt * 64, n0 = nt * 64;
  int tid = threadIdx.x;
  for (int idx = tid; idx < 6144; idx += 256) {
    int r = idx / 96, k = idx - r * 96;
    size_t m = (size_t)(m0 + r);
    float v = (k < 64) ? x[m * 64 + k] : emb[m * 32 + (k - 64)];
    XeT[k][r] = v;
  }
  for (int idx = tid; idx < 6144; idx += 256) {
    int c = idx / 96, k = idx - c * 96;
    WT[k][c] = Wih[(size_t)(n0 + c) * 96 + k];
  }
  __syncthreads();
  int ty = tid >> 4, tx = tid & 15;
  int r0 = ty * 4, c0 = tx * 4;
  float acc[4][4] = {};
  for (int k = 0; k < 96; k++) {
    float4 a = *(const float4*)&XeT[k][r0];
    float4 w = *(const float4*)&WT[k][c0];
    float av[4] = {a.x, a.y, a.z, a.w};
    float wv[4] = {w.x, w.y, w.z, w.w};
#pragma unroll
    for (int i = 0; i < 4; i++)
#pragma unroll
      for (int jj = 0; jj < 4; jj++) acc[i][jj] += av[i] * wv[jj];
  }
#pragma unroll
  for (int i = 0; i < 4; i++) {
    size_t m = (size_t)(m0 + r0 + i);
#pragma unroll
    for (int jj = 0; jj < 4; jj++) {
      int col = n0 + c0 + jj;
      zx[m * 1024 + (size_t)col] = f16bits(acc[i][jj] + bias[col]);
    }
  }
}

// ---------------- k3: persistent per-batch LSTM, hybrid MFMA + dot4 ----------------
__global__ __launch_bounds__(1024, 4) void lstm_kernel(const unsigned short* __restrict__ zx,
                                                       const v4i* __restrict__ wpkA,
                                                       const int* __restrict__ wpkD,
                                                       float* __restrict__ out) {
  __shared__ __align__(16) char hq[2][256];
  const int t = threadIdx.x, b = blockIdx.x;
  const int w = t >> 6, lane = t & 63, q = lane >> 4, n = lane & 15;

  // MFMA A-frags (K low half): 8 x 16B = 32 regs (AGPR-class ok)
  v4i wfA[8];
#pragma unroll
  for (int i = 0; i < 8; i++) wfA[i] = wpkA[i * 1024 + t];
  // dot4 weights (K high half): 32 VGPR dwords
  int wfD[32];
  {
    const int* wd = wpkD + t * 32;
#pragma unroll
    for (int i = 0; i < 8; i++) *(v4i*)&wfD[i * 4] = *(const v4i*)&wd[i * 4];
  }

  if (t < 128) ((unsigned int*)hq)[t] = 0;   // zero both h buffers (2x256 i8)
  __syncthreads();

  // lane job: gate g = n&3, unit-in-quad m = n>>2 ; lane updates unit u = q*4 + (n&3)
  const int g = n & 3;
  const bool isg = (g == 2);
  const float sc = isg ? 2.88539008f : 1.44269504f;
  const float dq = 1.0f / (2032.0f * 127.0f);
  const int row = g * 256 + w * 16 + q * 4 + (n >> 2);
  const unsigned short* zp = zx + (size_t)b * (2048u * 1024u) + row;
  const bool wr4 = (n < 4);
  const int j = w * 16 + q * 4 + n;                     // unit for writer lanes (n<4)
  float* op = out + (size_t)b * (2048u * 256u) + j;
  char* hn0 = &hq[0][j];
  const int bp0 = (((lane & 0x30) | (g << 2)) << 2);    // bpermute byte base: gates of unit q*4+g

  float cst = 0.f, hlast = 0.f;
  unsigned short za = zp[0];
  unsigned short zb = zp[1024];

  for (int s = 0; s < 2048; s++) {
    const char* hc = hq[s & 1];
    int sp = s + 2; if (sp > 2047) sp = 2047;
    unsigned short zc = zp[(size_t)sp << 10];

    // --- MFMA half: K in [0,128). B-frags broadcast h chunk (all N cols = h) ---
    v4i acc[4];
    const v4i zero = {0, 0, 0, 0};
#pragma unroll
    for (int gg = 0; gg < 4; gg++) acc[gg] = zero;
#pragma unroll
    for (int c = 0; c < 2; c++) {
      v4i bq = *(const v4i*)(hc + c * 64 + q * 16);
#pragma unroll
      for (int gg = 0; gg < 4; gg++)
        acc[gg] = __builtin_amdgcn_mfma_i32_16x16x64_i8(wfA[gg * 2 + c], bq, acc[gg], 0, 0, 0);
    }
    // all D cols are replicas -> lane holds all 64 z-partials of the wave; select
    // acc[n&3][n>>2] via cndmask tree -> K-low partial for (unit q*4+(n>>2), gate n&3)
    v4i t01 = (n & 1) ? acc[1] : acc[0];
    v4i t23 = (n & 1) ? acc[3] : acc[2];
    v4i tg  = (n & 2) ? t23 : t01;
    int lo = (n & 8) ? tg[2] : tg[0];
    int hi = (n & 8) ? tg[3] : tg[1];
    int zi = (n & 4) ? hi : lo;

    // --- dot4 half: K in [128,256), per-lane weights for the SAME (unit,gate) ---
    int d0 = 0, d1 = 0, d2 = 0, d3 = 0;
#pragma unroll
    for (int p = 0; p < 4; p++) {
      v4i ha = *(const v4i*)(hc + 128 + p * 32);
      v4i hb = *(const v4i*)(hc + 128 + p * 32 + 16);
      const int* wd = &wfD[p * 8];
      d0 = DOT4(wd[0], ha[0], d0);
      d1 = DOT4(wd[1], ha[1], d1);
      d2 = DOT4(wd[2], ha[2], d2);
      d3 = DOT4(wd[3], ha[3], d3);
      d0 = DOT4(wd[4], hb[0], d0);
      d1 = DOT4(wd[5], hb[1], d1);
      d2 = DOT4(wd[6], hb[2], d2);
      d3 = DOT4(wd[7], hb[3], d3);
    }
    zi += (d0 + d1) + (d2 + d3);

    float z = (float)zi * dq + (float)__builtin_bit_cast(_Float16, za);
    float e = __builtin_amdgcn_exp2f(-sc * z);
    float r = __builtin_amdgcn_rcpf(1.f + e);
    float a = isg ? (2.f * r - 1.f) : r;       // gate g: tanh ; else sigmoid
    // gather i,f,g,o of unit q*4+(n&3)
    int ab = __builtin_bit_cast(int, a);
    float ai = __builtin_bit_cast(float, __builtin_amdgcn_ds_bpermute(bp0 + 0, ab));
    float af = __builtin_bit_cast(float, __builtin_amdgcn_ds_bpermute(bp0 + 4, ab));
    float ag = __builtin_bit_cast(float, __builtin_amdgcn_ds_bpermute(bp0 + 8, ab));
    float ao = __builtin_bit_cast(float, __builtin_amdgcn_ds_bpermute(bp0 + 12, ab));
    float cn = af * cst + ai * ag;
    float e2 = __builtin_amdgcn_exp2f(-2.88539008f * cn);
    float th = 2.f * __builtin_amdgcn_rcpf(1.f + e2) - 1.f;
    float h = ao * th;
    cst = cn;
    hlast = h;
    if (wr4) {
      hn0[((s & 1) ^ 1) * 256] = (char)(int)rintf(h * 127.0f);   // i8 h feedback
      op[(size_t)s * 256] = h;                                    // fp32 output
    }
    za = zb; zb = zc;
    __syncthreads();
  }
  if (wr4) {
    out[16777216u + (size_t)b * 256 + j] = hlast;          // final h
    out[16777216u + 8192u + (size_t)b * 256 + j] = cst;    // final c
  }
}

extern "C" void kernel_launch(void* const* d_in, const int* in_sizes, int n_in,
                              void* d_out, int out_size, void* d_ws, size_t ws_size,
                              hipStream_t stream) {
  const float* x = (const float*)d_in[0];
  const float* emb = (const float*)d_in[1];
  const float* W_ih = (const float*)d_in[2];
  const float* W_hh = (const float*)d_in[3];
  const float* bias = (const float*)d_in[4];
  float* out = (float*)d_out;
  char* ws = (char*)d_ws;

  unsigned short* zx = (unsigned short*)ws;
  uint4* wpkA = (uint4*)(ws + WPK_OFF);
  int* wpkD = (int*)(ws + WPK_OFF + 131072u);

  size_t need = (size_t)WPK_OFF + 262144u;
  if (ws_size < need) {
    fprintf(stderr, "kernel_launch: ws too small: %zu < %zu\n", ws_size, need);
  }

  pack_kernel<<<dim3(40), dim3(1024), 0, stream>>>(W_hh, wpkA, wpkD);
  zx_kernel<<<dim3(1024, 16), dim3(256), 0, stream>>>(x, emb, W_ih, bias, zx);
  lstm_kernel<<<dim3(32), dim3(1024), 0, stream>>>(zx, (const v4i*)wpkA, wpkD, out);
}

// Round 4
// 1822.172 us; speedup vs baseline: 1.4401x; 1.2527x over previous
//
#include <hip/hip_runtime.h>
#include <hip/hip_fp16.h>
#include <cstdio>

// EmbeddingCellLSTM: B=32, S=2048, IN=64, EMB=32, H=256, 4H=1024
//  k1 pack_kernel : W_hh fp32 -> i8 (scale 2032) A-fragments for mfma_i32_16x16x64_i8.
//  k2 zx_kernel   : zx = (concat(x,emb) @ W_ih^T + b) fp16; block = 64-row stripe, loops
//                   all 16 col-tiles so x/emb are staged ONCE (was re-read 16x = 2GB).
//  k3 lstm_kernel : round-0 verified structure (32 blocks x 16 waves, W register-resident,
//                   256 i8 MFMAs/step, cndmask select, bpermute gate gather) PLUS
//                   wave-priority stagger: same-SIMD waves at prio 3,2,1,0 so the MFMA
//                   phase serializes across waves and each wave's VALU tail overlaps the
//                   other waves' MFMAs. Model: step = 1306 (matrix drain) + 640 (tail
//                   drain, additive today) + sync; stagger hides ~480 of the tail.
//  [dot4/hybrid removed: measured VALU-issue cost of 32 dot4 + AGPR copies (2326 cyc/step)
//   exceeds pure-MFMA's 2015; v_dot4 ~64 MAC/cyc/SIMD vs MFMA 802.]

#define WPK_OFF (134217728u)   // zx = 32*2048*1024*2 bytes, then wpk 256 KB

typedef int v4i __attribute__((ext_vector_type(4)));

static __device__ __forceinline__ unsigned short f16bits(float v) {
  _Float16 h = (_Float16)v;
  return __builtin_bit_cast(unsigned short, h);
}

// ---------------- k1: pack W_hh -> i8 MFMA A-fragments ----------------
// tile = g*4+c ; thread t -> w=t>>6, lane: m=lane&15 (row), q=lane>>4
// A[m][k]: k = c*64 + q*16 + j (j=0..15, byte j of the 16B frag)
// row = g*256 + 16w + m ; wq = rint(w * 2032), |w| < 1/16 -> |wq| <= 127
__global__ __launch_bounds__(1024) void pack_kernel(const float* __restrict__ Whh,
                                                    uint4* __restrict__ wpk) {
  int tile = blockIdx.x;            // 0..15
  int g = tile >> 2, c = tile & 3;
  int t = threadIdx.x;
  int w = t >> 6, lane = t & 63, m = lane & 15, q = lane >> 4;
  int row = g * 256 + w * 16 + m;
  const float* src = Whh + row * 256 + c * 64 + q * 16;
  unsigned int pk[4];
#pragma unroll
  for (int d = 0; d < 4; d++) {
    unsigned int v = 0;
#pragma unroll
    for (int e = 0; e < 4; e++) {
      int qv = (int)rintf(src[d * 4 + e] * 2032.0f);
      v |= ((unsigned int)(qv & 255)) << (8 * e);
    }
    pk[d] = v;
  }
  uint4 o; o.x = pk[0]; o.y = pk[1]; o.z = pk[2]; o.w = pk[3];
  wpk[tile * 1024 + t] = o;
}

// ---------------- k2: zx = concat(x,emb) @ W_ih^T + b (fp16, natural row order) ----------------
// One block per 64-row stripe; x/emb staged once, 16 column tiles looped in-block.
__global__ __launch_bounds__(256) void zx_kernel(const float* __restrict__ x,
                                                 const float* __restrict__ emb,
                                                 const float* __restrict__ Wih,
                                                 const float* __restrict__ bias,
                                                 unsigned short* __restrict__ zx) {
  __shared__ __align__(16) float XeT[96][68];
  __shared__ __align__(16) float WT[96][68];
  int mt = blockIdx.x;              // 0..1023
  int m0 = mt * 64;
  int tid = threadIdx.x;
  for (int idx = tid; idx < 6144; idx += 256) {
    int r = idx / 96, k = idx - r * 96;
    size_t m = (size_t)(m0 + r);
    float v = (k < 64) ? x[m * 64 + k] : emb[m * 32 + (k - 64)];
    XeT[k][r] = v;
  }
  int ty = tid >> 4, tx = tid & 15;
  int r0 = ty * 4, c0 = tx * 4;
  for (int nt = 0; nt < 16; nt++) {
    int n0 = nt * 64;
    __syncthreads();                // protect WT vs previous iter's readers (covers XeT stage on iter 0)
    for (int idx = tid; idx < 6144; idx += 256) {
      int c = idx / 96, k = idx - c * 96;
      WT[k][c] = Wih[(size_t)(n0 + c) * 96 + k];
    }
    __syncthreads();
    float acc[4][4] = {};
    for (int k = 0; k < 96; k++) {
      float4 a = *(const float4*)&XeT[k][r0];
      float4 wv4 = *(const float4*)&WT[k][c0];
      float av[4] = {a.x, a.y, a.z, a.w};
      float wv[4] = {wv4.x, wv4.y, wv4.z, wv4.w};
#pragma unroll
      for (int i = 0; i < 4; i++)
#pragma unroll
        for (int jj = 0; jj < 4; jj++) acc[i][jj] += av[i] * wv[jj];
    }
#pragma unroll
    for (int i = 0; i < 4; i++) {
      size_t m = (size_t)(m0 + r0 + i);
#pragma unroll
      for (int jj = 0; jj < 4; jj++) {
        int col = n0 + c0 + jj;
        zx[m * 1024 + (size_t)col] = f16bits(acc[i][jj] + bias[col]);
      }
    }
  }
}

// ---------------- k3: persistent per-batch LSTM (i8 MFMA, register-resident W) ----------------
__global__ __launch_bounds__(1024, 4) void lstm_kernel(const unsigned short* __restrict__ zx,
                                                       const v4i* __restrict__ wpk,
                                                       float* __restrict__ out) {
  __shared__ __align__(16) char hq[2][256];
  const int t = threadIdx.x, b = blockIdx.x;
  const int w = t >> 6, lane = t & 63, q = lane >> 4, n = lane & 15;

  // full W_hh residency: 16 frags x 16B i8 = 64 regs (A-operand; AGPR-friendly)
  v4i wf[16];
#pragma unroll
  for (int i = 0; i < 16; i++) wf[i] = wpk[i * 1024 + t];

  if (t < 128) ((unsigned int*)hq)[t] = 0;   // zero both h buffers (2x256 i8)
  __syncthreads();

  // wave-priority stagger: same-SIMD waves get prio 3,2,1,0 so MFMA-phase entry
  // serializes across waves and VALU tails hide under other waves' MFMAs.
  // Robust to either wave->SIMD mapping (w&3 or w>>2): XOR makes the intra-SIMD
  // index vary 0..3 under both.
  {
    int pr = 3 - (((w >> 2) ^ w) & 3);
    if (pr == 3) __builtin_amdgcn_s_setprio(3);
    else if (pr == 2) __builtin_amdgcn_s_setprio(2);
    else if (pr == 1) __builtin_amdgcn_s_setprio(1);
  }

  // lane job: gate g = n&3, row-in-quad m = n>>2 ; lane updates unit u = q*4 + (n&3)
  const int g = n & 3;
  const bool isg = (g == 2);
  const float sc = isg ? 2.88539008f : 1.44269504f;
  const float dq = 1.0f / (2032.0f * 127.0f);
  const int row = g * 256 + w * 16 + q * 4 + (n >> 2);
  const unsigned short* zp = zx + (size_t)b * (2048u * 1024u) + row;
  const bool wr4 = (n < 4);
  const int j = w * 16 + q * 4 + n;                     // unit for writer lanes (n<4)
  float* op = out + (size_t)b * (2048u * 256u) + j;
  char* hn0 = &hq[0][j];
  const int bp0 = (((lane & 0x30) | (g << 2)) << 2);    // bpermute byte base: gates of unit q*4+g

  float cst = 0.f, hlast = 0.f;
  unsigned short za = zp[0];
  unsigned short zb = zp[1024];

  for (int s = 0; s < 2048; s++) {
    const char* hc = hq[s & 1];
    int sp = s + 2; if (sp > 2047) sp = 2047;
    unsigned short zc = zp[(size_t)sp << 10];

    // B-frags: broadcast h_q chunk (16B per 16-lane group -> all N cols = h)
    v4i bq[4];
#pragma unroll
    for (int c = 0; c < 4; c++) bq[c] = *(const v4i*)(hc + c * 64 + q * 16);

    v4i acc[4];
    const v4i zero = {0, 0, 0, 0};
#pragma unroll
    for (int gg = 0; gg < 4; gg++) acc[gg] = zero;
#pragma unroll
    for (int c = 0; c < 4; c++)
#pragma unroll
      for (int gg = 0; gg < 4; gg++)
        acc[gg] = __builtin_amdgcn_mfma_i32_16x16x64_i8(wf[gg * 4 + c], bq[c], acc[gg], 0, 0, 0);

    // all D cols are replicas -> lane already holds all 64 z of the wave.
    // select acc[n&3][n>>2] via cndmask tree
    v4i t01 = (n & 1) ? acc[1] : acc[0];
    v4i t23 = (n & 1) ? acc[3] : acc[2];
    v4i tg  = (n & 2) ? t23 : t01;
    int lo = (n & 8) ? tg[2] : tg[0];
    int hi = (n & 8) ? tg[3] : tg[1];
    int zi = (n & 4) ? hi : lo;

    float z = (float)zi * dq + (float)__builtin_bit_cast(_Float16, za);
    float e = __builtin_amdgcn_exp2f(-sc * z);
    float r = __builtin_amdgcn_rcpf(1.f + e);
    float a = isg ? (2.f * r - 1.f) : r;       // gate g: tanh ; else sigmoid
    // gather i,f,g,o of unit q*4+(n&3)
    int ab = __builtin_bit_cast(int, a);
    float ai = __builtin_bit_cast(float, __builtin_amdgcn_ds_bpermute(bp0 + 0, ab));
    float af = __builtin_bit_cast(float, __builtin_amdgcn_ds_bpermute(bp0 + 4, ab));
    float ag = __builtin_bit_cast(float, __builtin_amdgcn_ds_bpermute(bp0 + 8, ab));
    float ao = __builtin_bit_cast(float, __builtin_amdgcn_ds_bpermute(bp0 + 12, ab));
    float cn = af * cst + ai * ag;
    float e2 = __builtin_amdgcn_exp2f(-2.88539008f * cn);
    float th = 2.f * __builtin_amdgcn_rcpf(1.f + e2) - 1.f;
    float h = ao * th;
    cst = cn;
    hlast = h;
    if (wr4) {
      hn0[((s & 1) ^ 1) * 256] = (char)(int)rintf(h * 127.0f);   // i8 h feedback
      op[(size_t)s * 256] = h;                                    // fp32 output
    }
    za = zb; zb = zc;
    __syncthreads();
  }
  if (wr4) {
    out[16777216u + (size_t)b * 256 + j] = hlast;          // final h
    out[16777216u + 8192u + (size_t)b * 256 + j] = cst;    // final c
  }
}

extern "C" void kernel_launch(void* const* d_in, const int* in_sizes, int n_in,
                              void* d_out, int out_size, void* d_ws, size_t ws_size,
                              hipStream_t stream) {
  const float* x = (const float*)d_in[0];
  const float* emb = (const float*)d_in[1];
  const float* W_ih = (const float*)d_in[2];
  const float* W_hh = (const float*)d_in[3];
  const float* bias = (const float*)d_in[4];
  float* out = (float*)d_out;
  char* ws = (char*)d_ws;

  unsigned short* zx = (unsigned short*)ws;
  uint4* wpk = (uint4*)(ws + WPK_OFF);

  size_t need = (size_t)WPK_OFF + 262144u;
  if (ws_size < need) {
    fprintf(stderr, "kernel_launch: ws too small: %zu < %zu\n", ws_size, need);
  }

  pack_kernel<<<dim3(16), dim3(1024), 0, stream>>>(W_hh, wpk);
  zx_kernel<<<dim3(1024), dim3(256), 0, stream>>>(x, emb, W_ih, bias, zx);
  lstm_kernel<<<dim3(32), dim3(1024), 0, stream>>>(zx, (const v4i*)wpk, out);
}